// Round 10
// baseline (1391.999 us; speedup 1.0000x reference)
//
#include <hip/hip_runtime.h>
#include <stdint.h>

// GraphSAGE fused layer, MI355X (gfx950). All tensors fp32.
// N=16384, D=64, adj = binary fp32 mask (1.074 GB), avg deg ~32.
// Evidence matrix (R2-R9): wave-per-row pattern caps ~4 TB/s regardless of
// processing; flat pattern + zero processing = 7.3 TB/s (R8 probe); flat +
// atomic-return waits = 3.5 (R6, vmcnt drains). R10 tests flat + CLEAN:
//   Phase A: probe-shaped streaming compress adj -> 32 MB bitmap (4-bit mask
//            per 16-B chunk). No atomics, no ballots, no result-dependent
//            waits. Every dword written -> no init needed.
//   Phase B: wave-per-row: bitmap -> ballot-compacted (chunk,mask) LDS list
//            (R9-validated decode) -> gather X -> GEMV -> ReLU -> L2-norm.

#define NROWS    16384
#define DDIM     64
#define MAXCHUNK 256
#define PA_BLOCKS 8192
#define PB_BLOCKS 4096
#define PA_WAVES ((size_t)PA_BLOCKS * 4)   // 32768
#define SPANS    ((size_t)1 << 17)         // 131072 spans of 8 KB (512 chunks)

typedef uint32_t u32x4 __attribute__((ext_vector_type(4)));

// ---------------- Phase A: adj -> bitmap (one dword per lane per span) -------
__device__ __forceinline__ void ld_span(const u32x4* __restrict__ p, size_t s,
                                        int lane, u32x4 b[8]) {
#pragma unroll
    for (int j = 0; j < 8; ++j) b[j] = p[s * 512 + j * 64 + lane];
}

__device__ __forceinline__ void st_span(uint32_t* __restrict__ bm, size_t s,
                                        int lane, const u32x4 b[8]) {
    uint32_t m = 0;
#pragma unroll
    for (int j = 0; j < 8; ++j) {
        const u32x4 v = b[j];
        // adj values are exactly 0.0f (all-zero bits) or 1.0f (0x3F800000, bit29 set)
        const uint32_t nib = ((v.x >> 29) & 1u) | ((v.y >> 28) & 2u)
                           | ((v.z >> 27) & 4u) | ((v.w >> 26) & 8u);
        m |= nib << (4 * j);
    }
    bm[s * 64 + lane] = m;     // coalesced 256 B per wave, fire-and-forget
}

__global__ __launch_bounds__(256, 4) void adj_to_bitmap(
    const float* __restrict__ adj, uint32_t* __restrict__ bm)
{
    const int    lane = threadIdx.x & 63;
    const size_t wv   = ((size_t)blockIdx.x * 256 + threadIdx.x) >> 6;  // 0..32767
    const u32x4* p    = reinterpret_cast<const u32x4*>(adj);

    const size_t s0 = wv,                 s1 = wv + PA_WAVES,
                 s2 = wv + 2 * PA_WAVES,  s3 = wv + 3 * PA_WAVES;

    u32x4 A[8], B[8];                     // ping-pong: 8 loads always in flight
    ld_span(p, s0, lane, A);
    ld_span(p, s1, lane, B);
    st_span(bm, s0, lane, A);
    ld_span(p, s2, lane, A);
    st_span(bm, s1, lane, B);
    ld_span(p, s3, lane, B);
    st_span(bm, s2, lane, A);
    st_span(bm, s3, lane, B);
}

// ---------------- Phase B: bitmap -> aggregate + GEMV + ReLU + L2-norm -------
__global__ __launch_bounds__(256, 4) void sage_agg(
    const float*    __restrict__ X,     // (N, 64)
    const uint32_t* __restrict__ bm,    // (SPANS, 64) dwords
    const float*    __restrict__ W,     // (128, 64) row-major, cache-hot
    const float*    __restrict__ bias,  // (64,)
    float*          __restrict__ out)   // (N, 64)
{
    __shared__ int   slist[4][MAXCHUNK];  // packed (chunkInRow<<4)|mask4
    __shared__ float scat[4][2 * DDIM];

    const int tid  = threadIdx.x;
    const int lane = tid & 63;
    const int w    = tid >> 6;
    const int row  = blockIdx.x * 4 + w;      // one wave per row

    const float bv = bias[lane];

    uint32_t dw[8];                            // lane's dwords for the 8 spans
#pragma unroll
    for (int sp = 0; sp < 8; ++sp)
        dw[sp] = bm[((size_t)row * 8 + sp) * 64 + lane];

    int cnt = 0;                               // wave-uniform entry count
#pragma unroll 1
    for (int sp = 0; sp < 8; ++sp) {
#pragma unroll
        for (int j = 0; j < 8; ++j) {
            const uint32_t nib = (dw[sp] >> (4 * j)) & 15u;
            const uint64_t bal = __ballot(nib != 0u);
            if (bal) {                         // wave-uniform branch
                const int prefix = __builtin_amdgcn_mbcnt_hi(
                    (uint32_t)(bal >> 32),
                    __builtin_amdgcn_mbcnt_lo((uint32_t)bal, 0));
                if (nib) {                     // exec-masked ds_write, no wait
                    const int pos = cnt + prefix;
                    if (pos < MAXCHUNK)
                        slist[w][pos] = ((sp * 512 + j * 64 + lane) << 4) | (int)nib;
                }
                cnt += (int)__popcll(bal);
            }
        }
    }
    __builtin_amdgcn_wave_barrier();           // order ds_write -> ds_read

    const int cn = (cnt < MAXCHUNK) ? cnt : MAXCHUNK;

    // Gather-accumulate neighbor X rows (mask branches are wave-uniform).
    float acc = 0.0f;
    int nnz = 0;                               // element count = rowsum(adj)
    for (int k = 0; k < cn; ++k) {
        const int e  = slist[w][k];            // LDS broadcast
        const int ci = e >> 4;                 // chunk index within row
        const uint32_t m = e & 15u;
        nnz += __popc(m);
        const float* xb = X + (size_t)ci * 4 * DDIM + lane;
        if (m & 1u) acc += xb[0 * DDIM];
        if (m & 2u) acc += xb[1 * DDIM];
        if (m & 4u) acc += xb[2 * DDIM];
        if (m & 8u) acc += xb[3 * DDIM];
    }

    const float xi = X[(size_t)row * DDIM + lane];
    const float h  = (acc + xi) / ((float)nnz + 1.0f);   // deg = rowsum+1 >= 1
    scat[w][lane]        = xi;
    scat[w][DDIM + lane] = h;
    __builtin_amdgcn_wave_barrier();

    // GEMV: z[d] = b[d] + sum_k cat[k] * W[k][d]; W is L1/L2-hot.
    float z0 = bv, z1 = 0.0f, z2 = 0.0f, z3 = 0.0f;
#pragma unroll 8
    for (int kk = 0; kk < 2 * DDIM; kk += 4) {
        z0 = fmaf(scat[w][kk + 0], W[(kk + 0) * DDIM + lane], z0);
        z1 = fmaf(scat[w][kk + 1], W[(kk + 1) * DDIM + lane], z1);
        z2 = fmaf(scat[w][kk + 2], W[(kk + 2) * DDIM + lane], z2);
        z3 = fmaf(scat[w][kk + 3], W[(kk + 3) * DDIM + lane], z3);
    }
    float z = (z0 + z1) + (z2 + z3);
    z = fmaxf(z, 0.0f);

    // Row L2-norm over the 64 lanes, normalize, store.
    float s2 = z * z;
#pragma unroll
    for (int off = 32; off >= 1; off >>= 1) s2 += __shfl_xor(s2, off);
    const float inv = 1.0f / fmaxf(sqrtf(s2), 1e-12f);
    out[(size_t)row * DDIM + lane] = z * inv;
}

extern "C" void kernel_launch(void* const* d_in, const int* in_sizes, int n_in,
                              void* d_out, int out_size, void* d_ws, size_t ws_size,
                              hipStream_t stream) {
    const float* X   = (const float*)d_in[0];
    const float* adj = (const float*)d_in[1];
    const float* W   = (const float*)d_in[2];
    const float* b   = (const float*)d_in[3];
    float* out = (float*)d_out;

    uint32_t* bm = (uint32_t*)d_ws;            // 32 MB bitmap, fully overwritten

    adj_to_bitmap<<<PA_BLOCKS, 256, 0, stream>>>(adj, bm);
    sage_agg<<<PB_BLOCKS, 256, 0, stream>>>(X, bm, W, b, out);
}